// Round 16
// baseline (173.766 us; speedup 1.0000x reference)
//
#include <hip/hip_runtime.h>

typedef __bf16 bf16x8 __attribute__((ext_vector_type(8)));
typedef float f32x4 __attribute__((ext_vector_type(4)));

__device__ __forceinline__ unsigned short f2bf(float f) {
    unsigned int u = __builtin_bit_cast(unsigned int, f);
    u += 0x7fff + ((u >> 16) & 1);   // round-to-nearest-even (finite inputs)
    return (unsigned short)(u >> 16);
}

// ---------------------------------------------------------------------------
// Stage a 128x64 A-tile + 128x64 B-tile (bf16) into lds[0..8191]/[8192..16383]
// via global_load_lds. Source chunk pre-swizzled c^(row&7); read side applies
// the same XOR (both-sides-or-neither, rule #21). 256 threads x 4 iters.
// ---------------------------------------------------------------------------
__device__ __forceinline__ void stage_pair(
    const unsigned short* __restrict__ Ap, int lda,
    const unsigned short* __restrict__ Bp, int ldb,
    unsigned short* lds, int k0, int tid)
{
#pragma unroll
    for (int it = 0; it < 4; ++it) {
        int li = it * 256 + tid;          // 0..1023: row = li>>3, chunk = li&7
        int row = li >> 3;
        int sc = ((li & 7) ^ (row & 7)) * 8;
        __builtin_amdgcn_global_load_lds(
            (const __attribute__((address_space(1))) void*)(Ap + (long)row * lda + k0 + sc),
            (__attribute__((address_space(3))) void*)&lds[li * 8], 16, 0, 0);
        __builtin_amdgcn_global_load_lds(
            (const __attribute__((address_space(1))) void*)(Bp + (long)row * ldb + k0 + sc),
            (__attribute__((address_space(3))) void*)&lds[8192 + li * 8], 16, 0, 0);
    }
}

// Stage just one 128x64 A-tile (8192 el) into buf (256 thr).
__device__ __forceinline__ void stage_one(
    const unsigned short* __restrict__ Ap, int lda,
    unsigned short* buf, int k0, int tid)
{
#pragma unroll
    for (int it = 0; it < 4; ++it) {
        int li = it * 256 + tid;
        int row = li >> 3;
        int sc = ((li & 7) ^ (row & 7)) * 8;
        __builtin_amdgcn_global_load_lds(
            (const __attribute__((address_space(1))) void*)(Ap + (long)row * lda + k0 + sc),
            (__attribute__((address_space(3))) void*)&buf[li * 8], 16, 0, 0);
    }
}

// ---------------------------------------------------------------------------
// One 64-deep K-step from a staged tile pair (swizzled read), 4-wave form.
// ---------------------------------------------------------------------------
__device__ __forceinline__ void compute_tile(
    const unsigned short* lds, int lane, int wm, int wn, f32x4 (&acc)[4][4])
{
#pragma unroll
    for (int kk = 0; kk < 2; ++kk) {
        const int cl = kk * 4 + (lane >> 4);
        bf16x8 af[4], bfr[4];
#pragma unroll
        for (int m = 0; m < 4; ++m) {
            int row = wm + m * 16 + (lane & 15);
            af[m] = *(const bf16x8*)&lds[row * 64 + ((cl ^ (row & 7)) * 8)];
        }
#pragma unroll
        for (int n = 0; n < 4; ++n) {
            int row = wn + n * 16 + (lane & 15);
            bfr[n] = *(const bf16x8*)&lds[8192 + row * 64 + ((cl ^ (row & 7)) * 8)];
        }
#pragma unroll
        for (int m = 0; m < 4; ++m)
#pragma unroll
            for (int n = 0; n < 4; ++n)
                acc[m][n] = __builtin_amdgcn_mfma_f32_16x16x32_bf16(af[m], bfr[n], acc[m][n], 0, 0, 0);
    }
}

// Like compute_tile but B-fragments come from a [rows][256] swizzled LDS
// buffer at K-offset k0 (A from a staged 128x64-style buffer, 64-wide rows).
__device__ __forceinline__ void compute_bsc(
    const unsigned short* bufA, const unsigned short* Sc, int k0,
    int lane, int wm, int wn, f32x4 (&acc)[4][4])
{
#pragma unroll
    for (int kk = 0; kk < 2; ++kk) {
        const int cl = kk * 4 + (lane >> 4);
        bf16x8 af[4], bfr[4];
#pragma unroll
        for (int m = 0; m < 4; ++m) {
            int row = wm + m * 16 + (lane & 15);
            af[m] = *(const bf16x8*)&bufA[row * 64 + ((cl ^ (row & 7)) * 8)];
        }
#pragma unroll
        for (int n = 0; n < 4; ++n) {
            int row = wn + n * 16 + (lane & 15);
            bfr[n] = *(const bf16x8*)&Sc[row * 256 + k0 + ((cl ^ (row & 7)) * 8)];
        }
#pragma unroll
        for (int m = 0; m < 4; ++m)
#pragma unroll
            for (int n = 0; n < 4; ++n)
                acc[m][n] = __builtin_amdgcn_mfma_f32_16x16x32_bf16(af[m], bfr[n], acc[m][n], 0, 0, 0);
    }
}

// ---------------------------------------------------------------------------
// Fused conversions: blocks [0,8192): X,H fp32->bf16 streaming;
// blocks [8192,10496): Wcat[g][q][512]=[Wgx|Wgh] bf16 + Woc bf16.
// ---------------------------------------------------------------------------
__global__ __launch_bounds__(256)
void cvt_all(const float* __restrict__ X, const float* __restrict__ H,
             unsigned short* __restrict__ XHb,
             const float* __restrict__ fx, const float* __restrict__ ix,
             const float* __restrict__ ox, const float* __restrict__ gx,
             const float* __restrict__ fh, const float* __restrict__ ih,
             const float* __restrict__ oh, const float* __restrict__ gh,
             const float* __restrict__ oc,
             unsigned short* __restrict__ Wcat, unsigned short* __restrict__ Wocb)
{
    int bid = blockIdx.x;
    if (bid < 8192) {
        long e = ((long)bid * 256 + threadIdx.x) * 8;
        const float* s = (e < 8388608) ? (X + e) : (H + (e - 8388608));
        float4 a = *(const float4*)s;
        float4 c = *(const float4*)(s + 4);
        uint4 uv;
        uv.x = (unsigned)f2bf(a.x) | ((unsigned)f2bf(a.y) << 16);
        uv.y = (unsigned)f2bf(a.z) | ((unsigned)f2bf(a.w) << 16);
        uv.z = (unsigned)f2bf(c.x) | ((unsigned)f2bf(c.y) << 16);
        uv.w = (unsigned)f2bf(c.z) | ((unsigned)f2bf(c.w) << 16);
        *(uint4*)&XHb[e] = uv;
    } else {
        int idx = (bid - 8192) * 256 + threadIdx.x;
        if (idx < 524288) {
            int g = idx >> 17;
            int rem = idx & 131071;
            int q = rem >> 9;
            int j = rem & 511;
            const float* xs = (g == 0) ? fx : (g == 1) ? ix : (g == 2) ? ox : gx;
            const float* hs = (g == 0) ? fh : (g == 1) ? ih : (g == 2) ? oh : gh;
            float v = (j < 256) ? xs[q * 256 + j] : hs[q * 256 + (j - 256)];
            Wcat[idx] = f2bf(v);
        } else if (idx < 589824) {
            int k = idx - 524288;
            Wocb[k] = f2bf(oc[k]);
        }
    }
}

// ---------------------------------------------------------------------------
// Stage 1, B-panel-resident (read-once): block = (b, hf, ti-half 128 i rows),
// all 256 q, loops all 4 gates over ONE resident XHb panel:
//   S_T[g][b][q][hf*256+ti+i] = sum_j Wcat[g][q][hf*256+j] * M_hf[b][ti+i][j]
// B (M panel, 128x256) resident in LDS (64KB, swizzled); A (Wcat, 256 q x 64)
// staged dbuf 2x32KB. 512 thr / 8 waves (q 4 x i 2 tiles of 64x64).
// grid (2,128,2) = 512 blocks, bijective XCD swizzle, 128KB LDS (1 blk/CU).
// ---------------------------------------------------------------------------
__global__ __launch_bounds__(512)
void gemm_s1r(const unsigned short* __restrict__ Wcat,
              const unsigned short* __restrict__ XHb,
              unsigned short* __restrict__ Tcat)
{
    __shared__ alignas(16) unsigned short lds[65536]; // B 32768 | A0 16384 | A1 16384

    const int tid = threadIdx.x;
    const int lane = tid & 63;
    const int w = tid >> 6;            // 0..7

    int d = blockIdx.x + 2 * blockIdx.y + 256 * blockIdx.z;  // 0..511
    int swz = (d & 7) * 64 + (d >> 3);                       // bijective (512%8==0)
    const int ti = (swz & 1) * 128;
    const int b = (swz >> 1) & 127;
    const int hf = swz >> 8;
    const int wm = (w >> 1) * 64;      // q offset (0..192)
    const int wn = (w & 1) * 64;       // i offset (0 or 64)

    const unsigned short* Bsrc = XHb + (long)hf * 8388608 + (long)b * 65536 + (long)ti * 256;
    unsigned short* Bres = lds;                       // [128][256] swizzled
    unsigned short* Abuf0 = lds + 32768;
    unsigned short* Abuf1 = lds + 49152;

    // stage resident B panel: 4096 chunks, pre-swizzled source, linear dest
#pragma unroll
    for (int it = 0; it < 8; ++it) {
        int li = it * 512 + tid;       // 0..4095: row = li>>5, ck = li&31
        int row = li >> 5;
        int ck = li & 31;
        int srccol = (ck & ~7) * 8 + (((ck & 7) ^ (row & 7)) * 8);
        __builtin_amdgcn_global_load_lds(
            (const __attribute__((address_space(1))) void*)(Bsrc + (long)row * 256 + srccol),
            (__attribute__((address_space(3))) void*)&Bres[li * 8], 16, 0, 0);
    }

    // stage A(u): gate = u>>2, t = u&3; A rows = 256 q x 64 j-chunk
    auto stageA = [&](int u, unsigned short* buf) {
        int gate = u >> 2;
        int t = u & 3;
        const unsigned short* Ap = Wcat + (long)gate * 131072 + hf * 256 + t * 64;
#pragma unroll
        for (int it = 0; it < 4; ++it) {
            int li = it * 512 + tid;   // 0..2047: row = li>>3 (0..255), ck = li&7
            int row = li >> 3;
            int sc = ((li & 7) ^ (row & 7)) * 8;
            __builtin_amdgcn_global_load_lds(
                (const __attribute__((address_space(1))) void*)(Ap + (long)row * 512 + sc),
                (__attribute__((address_space(3))) void*)&buf[li * 8], 16, 0, 0);
        }
    };

    f32x4 acc[4][4];
#pragma unroll
    for (int m = 0; m < 4; ++m)
#pragma unroll
        for (int n = 0; n < 4; ++n)
            acc[m][n] = (f32x4){0.f, 0.f, 0.f, 0.f};

    const int r0 = (lane >> 4) * 4;
    const int c0 = lane & 15;

    stageA(0, Abuf0);
    for (int u = 0; u < 16; ++u) {
        __syncthreads();   // loads(u) landed; all waves done compute(u-1)
        if (u + 1 < 16) stageA(u + 1, (u & 1) ? Abuf0 : Abuf1);
        const unsigned short* bufA = (u & 1) ? Abuf1 : Abuf0;
        compute_bsc(bufA, Bres, (u & 3) * 64, lane, wm, wn, acc);  // acc[q][i]
        if ((u & 3) == 3) {            // gate finished: write S_T[gate]
            int gate = u >> 2;
            unsigned short* Cb = Tcat + (long)gate * 16777216 + (long)b * 131072;
#pragma unroll
            for (int m = 0; m < 4; ++m)
#pragma unroll
                for (int n = 0; n < 4; ++n)
#pragma unroll
                    for (int r = 0; r < 4; ++r) {
                        int row = wm + m * 16 + r0 + r;                    // q
                        int col = hf * 256 + ti + wn + n * 16 + c0;        // i'
                        Cb[(long)row * 512 + col] = f2bf(acc[m][n][r]);
                        acc[m][n][r] = 0.f;
                    }
        }
    }
}

// ---------------------------------------------------------------------------
// Stage 2, Tcat-read-once: block = 256 o x 128 q (q-halves partition Tcat),
// all 4 gates (K=2048, 32 steps of 64, 2-phase dbuf).
//   out_c = cell + relu(f)+relu(i)+relu(g) (fp32 + bf16 copy); out_h = relu(o)
// A = Wcat[gv] all 256 o (32KB/step, L2-resident); B = Tcat[gv][b][q-half]
// (16KB/step, read ONCE). 512 thr / 8 waves (o 4 x q 2 tiles), 96KB LDS.
// grid (2,128) = 256 blocks, bijective XCD swizzle.
// ---------------------------------------------------------------------------
__global__ __launch_bounds__(512)
void gemm_gateBq(const unsigned short* __restrict__ Tcat,
                 const unsigned short* __restrict__ Wcat,
                 const float* __restrict__ cell,
                 float* __restrict__ out_c, float* __restrict__ out_h,
                 unsigned short* __restrict__ cb16)
{
    __shared__ alignas(16) unsigned short lds[49152];   // 2 x (A 16384 | B 8192)

    const int tid = threadIdx.x;
    const int lane = tid & 63;
    const int w = tid >> 6;            // 0..7

    int orig = blockIdx.x + 2 * blockIdx.y;              // 0..255
    int swz = (orig & 7) * 32 + (orig >> 3);             // bijective (256%8==0)
    const int b = swz >> 1;
    const int qh = (swz & 1) * 128;
    const int wm = (w >> 1) * 64;      // o offset (0..192)
    const int wn = (w & 1) * 64;       // q offset (0 or 64)

    const unsigned short* Bb = Tcat + (long)b * 131072 + (long)qh * 512;

    // stage step u into buf: A = Wcat[gv] 256x64, B = Tcat panel 128x64
    auto stage = [&](int u, unsigned short* buf) {
        int s = u >> 3;
        int gv = s ^ (s >> 1);                 // {0,1,3,2} = f,i,g,o
        int k0 = (u & 7) * 64;
        const unsigned short* Ap = Wcat + (long)gv * 131072 + k0;
        const unsigned short* Bp = Bb + (long)gv * 16777216 + k0;
#pragma unroll
        for (int it = 0; it < 4; ++it) {
            int li = it * 512 + tid;           // A: 0..2047, row 0..255
            int row = li >> 3;
            int sc = ((li & 7) ^ (row & 7)) * 8;
            __builtin_amdgcn_global_load_lds(
                (const __attribute__((address_space(1))) void*)(Ap + (long)row * 512 + sc),
                (__attribute__((address_space(3))) void*)&buf[li * 8], 16, 0, 0);
        }
#pragma unroll
        for (int it = 0; it < 2; ++it) {
            int li = it * 512 + tid;           // B: 0..1023, row 0..127
            int row = li >> 3;
            int sc = ((li & 7) ^ (row & 7)) * 8;
            __builtin_amdgcn_global_load_lds(
                (const __attribute__((address_space(1))) void*)(Bp + (long)row * 512 + sc),
                (__attribute__((address_space(3))) void*)&buf[16384 + li * 8], 16, 0, 0);
        }
    };

    f32x4 accc[4][4], acc[4][4];
#pragma unroll
    for (int m = 0; m < 4; ++m)
#pragma unroll
        for (int n = 0; n < 4; ++n) {
            accc[m][n] = (f32x4){0.f, 0.f, 0.f, 0.f};
            acc[m][n] = (f32x4){0.f, 0.f, 0.f, 0.f};
        }

    stage(0, lds);
    for (int u = 0; u < 32; ++u) {
        __syncthreads();   // loads(u) landed; all waves done compute(u-1)
        if (u + 1 < 32) stage(u + 1, lds + ((u + 1) & 1) * 24576);
        const unsigned short* buf = lds + (u & 1) * 24576;
        // compute: A rows o (wm), B rows q (wn)
#pragma unroll
        for (int kk = 0; kk < 2; ++kk) {
            const int cl = kk * 4 + (lane >> 4);
            bf16x8 af[4], bfr[4];
#pragma unroll
            for (int m = 0; m < 4; ++m) {
                int row = wm + m * 16 + (lane & 15);
                af[m] = *(const bf16x8*)&buf[row * 64 + ((cl ^ (row & 7)) * 8)];
            }
#pragma unroll
            for (int n = 0; n < 4; ++n) {
                int row = wn + n * 16 + (lane & 15);
                bfr[n] = *(const bf16x8*)&buf[16384 + row * 64 + ((cl ^ (row & 7)) * 8)];
            }
#pragma unroll
            for (int m = 0; m < 4; ++m)
#pragma unroll
                for (int n = 0; n < 4; ++n)
                    acc[m][n] = __builtin_amdgcn_mfma_f32_16x16x32_bf16(af[m], bfr[n], acc[m][n], 0, 0, 0);
        }
        if ((u & 7) == 7 && u != 31) {         // fold f/i/g into accc
#pragma unroll
            for (int m = 0; m < 4; ++m)
#pragma unroll
                for (int n = 0; n < 4; ++n)
#pragma unroll
                    for (int r = 0; r < 4; ++r) {
                        float v = acc[m][n][r];
                        accc[m][n][r] += (v > 0.f ? v : 0.f);
                        acc[m][n][r] = 0.f;
                    }
        }
    }

    const float* cb = cell + (long)b * 65536;
    float* co = out_c + (long)b * 65536;
    float* ho = out_h + (long)b * 65536;
    unsigned short* cbo = cb16 + (long)b * 65536;
    const int r0 = (lane >> 4) * 4;
    const int c0 = lane & 15;
#pragma unroll
    for (int m = 0; m < 4; ++m)
#pragma unroll
        for (int n = 0; n < 4; ++n)
#pragma unroll
            for (int r = 0; r < 4; ++r) {
                int row = wm + m * 16 + r0 + r;        // o (0..255)
                int col = qh + wn + n * 16 + c0;       // q
                long idx = (long)row * 256 + col;
                float cv = accc[m][n][r] + cb[idx];
                co[idx] = cv;
                cbo[idx] = f2bf(cv);
                float v = acc[m][n][r];                // o-gate
                ho[idx] = (v > 0.f ? v : 0.f);
            }
}

// ---------------------------------------------------------------------------
// Merged Woc chain (r13 form): per (q-tile, batch) block:
//   Phase A: Sc[q_loc][i] = bf16( sum_j Woc[q][j] * c[b][i][j] )  (LDS)
//   Phase B: out_h[b][o][tq+q_loc] += relu( sum_i Woc[o][i] * Sc[q_loc][i] )
// grid (2,128) = 256 blocks, 256 thr, 128KB LDS.
// ---------------------------------------------------------------------------
__global__ __launch_bounds__(256)
void gemm_woc(const unsigned short* __restrict__ Wocb,
              const unsigned short* __restrict__ cb16,
              float* __restrict__ out_h)
{
    __shared__ alignas(16) unsigned short stg[32768];   // 2 x (A 8192 | B 8192)
    __shared__ alignas(16) unsigned short Sc[32768];    // [128][256] swizzled bf16

    const int tid = threadIdx.x;
    const int lane = tid & 63;
    const int w = tid >> 6;

    int orig = blockIdx.x + 2 * blockIdx.y;              // 0..255
    int swz = (orig & 7) * 32 + (orig >> 3);             // bijective (256%8==0)
    const int b = swz >> 1;
    const int tq = (swz & 1) * 128;
    const int wm = (w >> 1) * 64;
    const int wn = (w & 1) * 64;
    const int r0 = (lane >> 4) * 4;
    const int c0 = lane & 15;

    // ---- Phase A: build Sc (q-tile x 256 i) ----
#pragma unroll
    for (int t2 = 0; t2 < 2; ++t2) {
        const unsigned short* Ap = Wocb + (long)tq * 256;
        const unsigned short* Bp = cb16 + (long)b * 65536 + (long)(t2 * 128) * 256;

        f32x4 acc[4][4];
#pragma unroll
        for (int m = 0; m < 4; ++m)
#pragma unroll
            for (int n = 0; n < 4; ++n)
                acc[m][n] = (f32x4){0.f, 0.f, 0.f, 0.f};

        stage_pair(Ap, 256, Bp, 256, stg, 0, tid);
#pragma unroll
        for (int t = 0; t < 4; ++t) {
            __syncthreads();
            if (t + 1 < 4)
                stage_pair(Ap, 256, Bp, 256, stg + ((t + 1) & 1) * 16384, (t + 1) * 64, tid);
            compute_tile(stg + (t & 1) * 16384, lane, wm, wn, acc);  // acc[q_loc][i_loc]
        }
        // write acc -> Sc bf16, swizzled (chunk-XOR within each 64-el group)
#pragma unroll
        for (int m = 0; m < 4; ++m)
#pragma unroll
            for (int n = 0; n < 4; ++n)
#pragma unroll
                for (int r = 0; r < 4; ++r) {
                    int qrow = wm + m * 16 + r0 + r;             // 0..127
                    int icol = t2 * 128 + wn + n * 16 + c0;      // 0..255
                    int addr = qrow * 256 + (icol & ~63)
                             + ((((icol >> 3) & 7) ^ (qrow & 7)) * 8) + (icol & 7);
                    Sc[addr] = f2bf(acc[m][n][r]);
                }
    }

    // ---- Phase B: out_h[o][tq+q] += relu( Woc[o,:] . Sc[q,:] ) ----
    float* ho = out_h + (long)b * 65536;
#pragma unroll
    for (int ot = 0; ot < 2; ++ot) {
        const unsigned short* Ap = Wocb + (long)(ot * 128) * 256;

        f32x4 acc[4][4];
#pragma unroll
        for (int m = 0; m < 4; ++m)
#pragma unroll
            for (int n = 0; n < 4; ++n)
                acc[m][n] = (f32x4){0.f, 0.f, 0.f, 0.f};

        stage_one(Ap, 256, stg, 0, tid);
#pragma unroll
        for (int t = 0; t < 4; ++t) {
            __syncthreads();   // first iter also fences Sc writes from phase A
            if (t + 1 < 4)
                stage_one(Ap, 256, stg + ((t + 1) & 1) * 16384, (t + 1) * 64, tid);
            compute_bsc(stg + (t & 1) * 16384, Sc, t * 64, lane, wm, wn, acc);
        }
#pragma unroll
        for (int m = 0; m < 4; ++m)
#pragma unroll
            for (int n = 0; n < 4; ++n)
#pragma unroll
                for (int r = 0; r < 4; ++r) {
                    int orow = ot * 128 + wm + m * 16 + r0 + r;
                    int qcol = tq + wn + n * 16 + c0;
                    long idx = (long)orow * 256 + qcol;
                    float v = acc[m][n][r];
                    ho[idx] += (v > 0.f ? v : 0.f);
                }
    }
}

// ---------------------------------------------------------------------------
extern "C" void kernel_launch(void* const* d_in, const int* in_sizes, int n_in,
                              void* d_out, int out_size, void* d_ws, size_t ws_size,
                              hipStream_t stream)
{
    (void)in_sizes; (void)n_in; (void)out_size; (void)ws_size;

    const float* X    = (const float*)d_in[0];
    const float* H    = (const float*)d_in[1];
    const float* cell = (const float*)d_in[2];
    const float* Wxp[4] = {(const float*)d_in[3], (const float*)d_in[4],
                           (const float*)d_in[5], (const float*)d_in[6]};
    const float* Whp[4] = {(const float*)d_in[7], (const float*)d_in[8],
                           (const float*)d_in[9], (const float*)d_in[10]};
    const float* Wocf = (const float*)d_in[11];

    float* out_h = (float*)d_out;                  // [128][256][256]
    float* out_c = out_h + 8388608;                // [128][256][256]

    unsigned short* ws   = (unsigned short*)d_ws;  // bf16 elements (ws = 256 MiB)
    unsigned short* XHb  = ws;                     // 16,777,216 el [2][128][256][256]
    unsigned short* Wcat = ws + 16777216;          //    524,288 el [4][256][512]
    unsigned short* Wocb = ws + 17301504;          //     65,536 el
    unsigned short* Tcat = ws + 17367040;          // 67,108,864 el [4][128][256][512]
    unsigned short* cb16 = ws + 84475904;          //  8,388,608 el (c bf16, natural)

    // 1. all conversions (X,H streaming + weights)
    cvt_all<<<dim3(10496), 256, 0, stream>>>(X, H, XHb,
                                             Wxp[0], Wxp[1], Wxp[2], Wxp[3],
                                             Whp[0], Whp[1], Whp[2], Whp[3],
                                             Wocf, Wcat, Wocb);
    // 2. stage 1, B-resident read-once: S_T[g][b][q][i']
    gemm_s1r<<<dim3(2, 128, 2), 512, 0, stream>>>(Wcat, XHb, Tcat);
    // 3. stage 2, Tcat read-once: all 4 gates -> out_c (+bf16 copy), out_h
    gemm_gateBq<<<dim3(2, 128), 512, 0, stream>>>(Tcat, Wcat, cell, out_c, out_h, cb16);
    // 4. merged Woc chain: Sc in LDS, h = ogate + relu(Woc . (Woc . c^T)^T)
    gemm_woc<<<dim3(2, 128), 256, 0, stream>>>(Wocb, cb16, out_h);
}

// Round 17
// 168.806 us; speedup vs baseline: 1.0294x; 1.0294x over previous
//
#include <hip/hip_runtime.h>

typedef __bf16 bf16x8 __attribute__((ext_vector_type(8)));
typedef float f32x4 __attribute__((ext_vector_type(4)));

__device__ __forceinline__ unsigned short f2bf(float f) {
    unsigned int u = __builtin_bit_cast(unsigned int, f);
    u += 0x7fff + ((u >> 16) & 1);   // round-to-nearest-even (finite inputs)
    return (unsigned short)(u >> 16);
}
__device__ __forceinline__ float bf2f(unsigned short u) {
    unsigned int v = (unsigned int)u << 16;
    return __builtin_bit_cast(float, v);
}

// ---------------------------------------------------------------------------
// Stage a 128x64 A-tile + 128x64 B-tile (bf16) into lds[0..8191]/[8192..16383]
// via global_load_lds. Source chunk pre-swizzled c^(row&7); read side applies
// the same XOR (both-sides-or-neither, rule #21). 256 threads x 4 iters.
// ---------------------------------------------------------------------------
__device__ __forceinline__ void stage_pair(
    const unsigned short* __restrict__ Ap, int lda,
    const unsigned short* __restrict__ Bp, int ldb,
    unsigned short* lds, int k0, int tid)
{
#pragma unroll
    for (int it = 0; it < 4; ++it) {
        int li = it * 256 + tid;          // 0..1023: row = li>>3, chunk = li&7
        int row = li >> 3;
        int sc = ((li & 7) ^ (row & 7)) * 8;
        __builtin_amdgcn_global_load_lds(
            (const __attribute__((address_space(1))) void*)(Ap + (long)row * lda + k0 + sc),
            (__attribute__((address_space(3))) void*)&lds[li * 8], 16, 0, 0);
        __builtin_amdgcn_global_load_lds(
            (const __attribute__((address_space(1))) void*)(Bp + (long)row * ldb + k0 + sc),
            (__attribute__((address_space(3))) void*)&lds[8192 + li * 8], 16, 0, 0);
    }
}

// Stage just one 128x64 A-tile (8192 el) into buf (256 thr).
__device__ __forceinline__ void stage_one(
    const unsigned short* __restrict__ Ap, int lda,
    unsigned short* buf, int k0, int tid)
{
#pragma unroll
    for (int it = 0; it < 4; ++it) {
        int li = it * 256 + tid;
        int row = li >> 3;
        int sc = ((li & 7) ^ (row & 7)) * 8;
        __builtin_amdgcn_global_load_lds(
            (const __attribute__((address_space(1))) void*)(Ap + (long)row * lda + k0 + sc),
            (__attribute__((address_space(3))) void*)&buf[li * 8], 16, 0, 0);
    }
}

// ---------------------------------------------------------------------------
// One 64-deep K-step from a staged tile pair (swizzled read), 4-wave form.
// ---------------------------------------------------------------------------
__device__ __forceinline__ void compute_tile(
    const unsigned short* lds, int lane, int wm, int wn, f32x4 (&acc)[4][4])
{
#pragma unroll
    for (int kk = 0; kk < 2; ++kk) {
        const int cl = kk * 4 + (lane >> 4);
        bf16x8 af[4], bfr[4];
#pragma unroll
        for (int m = 0; m < 4; ++m) {
            int row = wm + m * 16 + (lane & 15);
            af[m] = *(const bf16x8*)&lds[row * 64 + ((cl ^ (row & 7)) * 8)];
        }
#pragma unroll
        for (int n = 0; n < 4; ++n) {
            int row = wn + n * 16 + (lane & 15);
            bfr[n] = *(const bf16x8*)&lds[8192 + row * 64 + ((cl ^ (row & 7)) * 8)];
        }
#pragma unroll
        for (int m = 0; m < 4; ++m)
#pragma unroll
            for (int n = 0; n < 4; ++n)
                acc[m][n] = __builtin_amdgcn_mfma_f32_16x16x32_bf16(af[m], bfr[n], acc[m][n], 0, 0, 0);
    }
}

// Like compute_tile but B-fragments come from a [rows][256] swizzled LDS
// buffer at K-offset k0 (A from a staged 128x64-style buffer, 64-wide rows).
__device__ __forceinline__ void compute_bsc(
    const unsigned short* bufA, const unsigned short* Sc, int k0,
    int lane, int wm, int wn, f32x4 (&acc)[4][4])
{
#pragma unroll
    for (int kk = 0; kk < 2; ++kk) {
        const int cl = kk * 4 + (lane >> 4);
        bf16x8 af[4], bfr[4];
#pragma unroll
        for (int m = 0; m < 4; ++m) {
            int row = wm + m * 16 + (lane & 15);
            af[m] = *(const bf16x8*)&bufA[row * 64 + ((cl ^ (row & 7)) * 8)];
        }
#pragma unroll
        for (int n = 0; n < 4; ++n) {
            int row = wn + n * 16 + (lane & 15);
            bfr[n] = *(const bf16x8*)&Sc[row * 256 + k0 + ((cl ^ (row & 7)) * 8)];
        }
#pragma unroll
        for (int m = 0; m < 4; ++m)
#pragma unroll
            for (int n = 0; n < 4; ++n)
                acc[m][n] = __builtin_amdgcn_mfma_f32_16x16x32_bf16(af[m], bfr[n], acc[m][n], 0, 0, 0);
    }
}

// ---------------------------------------------------------------------------
// Fused conversions: blocks [0,8192): X,H fp32->bf16 streaming;
// blocks [8192,10496): Wcat[g][q][512]=[Wgx|Wgh] bf16 + Woc bf16.
// ---------------------------------------------------------------------------
__global__ __launch_bounds__(256)
void cvt_all(const float* __restrict__ X, const float* __restrict__ H,
             unsigned short* __restrict__ XHb,
             const float* __restrict__ fx, const float* __restrict__ ix,
             const float* __restrict__ ox, const float* __restrict__ gx,
             const float* __restrict__ fh, const float* __restrict__ ih,
             const float* __restrict__ oh, const float* __restrict__ gh,
             const float* __restrict__ oc,
             unsigned short* __restrict__ Wcat, unsigned short* __restrict__ Wocb)
{
    int bid = blockIdx.x;
    if (bid < 8192) {
        long e = ((long)bid * 256 + threadIdx.x) * 8;
        const float* s = (e < 8388608) ? (X + e) : (H + (e - 8388608));
        float4 a = *(const float4*)s;
        float4 c = *(const float4*)(s + 4);
        uint4 uv;
        uv.x = (unsigned)f2bf(a.x) | ((unsigned)f2bf(a.y) << 16);
        uv.y = (unsigned)f2bf(a.z) | ((unsigned)f2bf(a.w) << 16);
        uv.z = (unsigned)f2bf(c.x) | ((unsigned)f2bf(c.y) << 16);
        uv.w = (unsigned)f2bf(c.z) | ((unsigned)f2bf(c.w) << 16);
        *(uint4*)&XHb[e] = uv;
    } else {
        int idx = (bid - 8192) * 256 + threadIdx.x;
        if (idx < 524288) {
            int g = idx >> 17;
            int rem = idx & 131071;
            int q = rem >> 9;
            int j = rem & 511;
            const float* xs = (g == 0) ? fx : (g == 1) ? ix : (g == 2) ? ox : gx;
            const float* hs = (g == 0) ? fh : (g == 1) ? ih : (g == 2) ? oh : gh;
            float v = (j < 256) ? xs[q * 256 + j] : hs[q * 256 + (j - 256)];
            Wcat[idx] = f2bf(v);
        } else if (idx < 589824) {
            int k = idx - 524288;
            Wocb[k] = f2bf(oc[k]);
        }
    }
}

// ---------------------------------------------------------------------------
// Stage 1, B-panel-resident (read-once): block = (b, hf, ti-half 128 i rows),
// all 256 q, loops all 4 gates over ONE resident XHb panel:
//   S_T[g][b][q][hf*256+ti+i] = sum_j Wcat[g][q][hf*256+j] * M_hf[b][ti+i][j]
// B (M panel, 128x256) resident in LDS (64KB, swizzled); A (Wcat, 256 q x 64)
// staged dbuf 2x32KB. 512 thr / 8 waves (q 4 x i 2 tiles of 64x64).
// grid (2,128,2) = 512 blocks, bijective XCD swizzle, 128KB LDS (1 blk/CU).
// ---------------------------------------------------------------------------
__global__ __launch_bounds__(512)
void gemm_s1r(const unsigned short* __restrict__ Wcat,
              const unsigned short* __restrict__ XHb,
              unsigned short* __restrict__ Tcat)
{
    __shared__ alignas(16) unsigned short lds[65536]; // B 32768 | A0 16384 | A1 16384

    const int tid = threadIdx.x;
    const int lane = tid & 63;
    const int w = tid >> 6;            // 0..7

    int d = blockIdx.x + 2 * blockIdx.y + 256 * blockIdx.z;  // 0..511
    int swz = (d & 7) * 64 + (d >> 3);                       // bijective (512%8==0)
    const int ti = (swz & 1) * 128;
    const int b = (swz >> 1) & 127;
    const int hf = swz >> 8;
    const int wm = (w >> 1) * 64;      // q offset (0..192)
    const int wn = (w & 1) * 64;       // i offset (0 or 64)

    const unsigned short* Bsrc = XHb + (long)hf * 8388608 + (long)b * 65536 + (long)ti * 256;
    unsigned short* Bres = lds;                       // [128][256] swizzled
    unsigned short* Abuf0 = lds + 32768;
    unsigned short* Abuf1 = lds + 49152;

    // stage resident B panel: 4096 chunks, pre-swizzled source, linear dest
#pragma unroll
    for (int it = 0; it < 8; ++it) {
        int li = it * 512 + tid;       // 0..4095: row = li>>5, ck = li&31
        int row = li >> 5;
        int ck = li & 31;
        int srccol = (ck & ~7) * 8 + (((ck & 7) ^ (row & 7)) * 8);
        __builtin_amdgcn_global_load_lds(
            (const __attribute__((address_space(1))) void*)(Bsrc + (long)row * 256 + srccol),
            (__attribute__((address_space(3))) void*)&Bres[li * 8], 16, 0, 0);
    }

    // stage A(u): gate = u>>2, t = u&3; A rows = 256 q x 64 j-chunk
    auto stageA = [&](int u, unsigned short* buf) {
        int gate = u >> 2;
        int t = u & 3;
        const unsigned short* Ap = Wcat + (long)gate * 131072 + hf * 256 + t * 64;
#pragma unroll
        for (int it = 0; it < 4; ++it) {
            int li = it * 512 + tid;   // 0..2047: row = li>>3 (0..255), ck = li&7
            int row = li >> 3;
            int sc = ((li & 7) ^ (row & 7)) * 8;
            __builtin_amdgcn_global_load_lds(
                (const __attribute__((address_space(1))) void*)(Ap + (long)row * 512 + sc),
                (__attribute__((address_space(3))) void*)&buf[li * 8], 16, 0, 0);
        }
    };

    f32x4 acc[4][4];
#pragma unroll
    for (int m = 0; m < 4; ++m)
#pragma unroll
        for (int n = 0; n < 4; ++n)
            acc[m][n] = (f32x4){0.f, 0.f, 0.f, 0.f};

    const int r0 = (lane >> 4) * 4;
    const int c0 = lane & 15;

    stageA(0, Abuf0);
    for (int u = 0; u < 16; ++u) {
        __syncthreads();   // loads(u) landed; all waves done compute(u-1)
        if (u + 1 < 16) stageA(u + 1, (u & 1) ? Abuf0 : Abuf1);
        const unsigned short* bufA = (u & 1) ? Abuf1 : Abuf0;
        compute_bsc(bufA, Bres, (u & 3) * 64, lane, wm, wn, acc);  // acc[q][i]
        if ((u & 3) == 3) {            // gate finished: write S_T[gate]
            int gate = u >> 2;
            unsigned short* Cb = Tcat + (long)gate * 16777216 + (long)b * 131072;
#pragma unroll
            for (int m = 0; m < 4; ++m)
#pragma unroll
                for (int n = 0; n < 4; ++n)
#pragma unroll
                    for (int r = 0; r < 4; ++r) {
                        int row = wm + m * 16 + r0 + r;                    // q
                        int col = hf * 256 + ti + wn + n * 16 + c0;        // i'
                        Cb[(long)row * 512 + col] = f2bf(acc[m][n][r]);
                        acc[m][n][r] = 0.f;
                    }
        }
    }
}

// ---------------------------------------------------------------------------
// Stage 2, Tcat-read-once: block = 256 o x 128 q (q-halves partition Tcat),
// all 4 gates (K=2048, 32 steps of 64, 2-phase dbuf).
//   out_c = cell + relu(f)+relu(i)+relu(g) (fp32 + bf16 copy);
//   og16  = bf16( relu(o-gate) )   [bf16 intermediate, consumed by gemm_woc]
// A = Wcat[gv] all 256 o (32KB/step, L2-resident); B = Tcat[gv][b][q-half]
// (16KB/step, read ONCE). 512 thr / 8 waves (o 4 x q 2 tiles), 96KB LDS.
// grid (2,128) = 256 blocks, bijective XCD swizzle.
// ---------------------------------------------------------------------------
__global__ __launch_bounds__(512)
void gemm_gateBq(const unsigned short* __restrict__ Tcat,
                 const unsigned short* __restrict__ Wcat,
                 const float* __restrict__ cell,
                 float* __restrict__ out_c,
                 unsigned short* __restrict__ og16,
                 unsigned short* __restrict__ cb16)
{
    __shared__ alignas(16) unsigned short lds[49152];   // 2 x (A 16384 | B 8192)

    const int tid = threadIdx.x;
    const int lane = tid & 63;
    const int w = tid >> 6;            // 0..7

    int orig = blockIdx.x + 2 * blockIdx.y;              // 0..255
    int swz = (orig & 7) * 32 + (orig >> 3);             // bijective (256%8==0)
    const int b = swz >> 1;
    const int qh = (swz & 1) * 128;
    const int wm = (w >> 1) * 64;      // o offset (0..192)
    const int wn = (w & 1) * 64;       // q offset (0 or 64)

    const unsigned short* Bb = Tcat + (long)b * 131072 + (long)qh * 512;

    // stage step u into buf: A = Wcat[gv] 256x64, B = Tcat panel 128x64
    auto stage = [&](int u, unsigned short* buf) {
        int s = u >> 3;
        int gv = s ^ (s >> 1);                 // {0,1,3,2} = f,i,g,o
        int k0 = (u & 7) * 64;
        const unsigned short* Ap = Wcat + (long)gv * 131072 + k0;
        const unsigned short* Bp = Bb + (long)gv * 16777216 + k0;
#pragma unroll
        for (int it = 0; it < 4; ++it) {
            int li = it * 512 + tid;           // A: 0..2047, row 0..255
            int row = li >> 3;
            int sc = ((li & 7) ^ (row & 7)) * 8;
            __builtin_amdgcn_global_load_lds(
                (const __attribute__((address_space(1))) void*)(Ap + (long)row * 512 + sc),
                (__attribute__((address_space(3))) void*)&buf[li * 8], 16, 0, 0);
        }
#pragma unroll
        for (int it = 0; it < 2; ++it) {
            int li = it * 512 + tid;           // B: 0..1023, row 0..127
            int row = li >> 3;
            int sc = ((li & 7) ^ (row & 7)) * 8;
            __builtin_amdgcn_global_load_lds(
                (const __attribute__((address_space(1))) void*)(Bp + (long)row * 512 + sc),
                (__attribute__((address_space(3))) void*)&buf[16384 + li * 8], 16, 0, 0);
        }
    };

    f32x4 accc[4][4], acc[4][4];
#pragma unroll
    for (int m = 0; m < 4; ++m)
#pragma unroll
        for (int n = 0; n < 4; ++n) {
            accc[m][n] = (f32x4){0.f, 0.f, 0.f, 0.f};
            acc[m][n] = (f32x4){0.f, 0.f, 0.f, 0.f};
        }

    stage(0, lds);
    for (int u = 0; u < 32; ++u) {
        __syncthreads();   // loads(u) landed; all waves done compute(u-1)
        if (u + 1 < 32) stage(u + 1, lds + ((u + 1) & 1) * 24576);
        const unsigned short* buf = lds + (u & 1) * 24576;
        // compute: A rows o (wm), B rows q (wn)
#pragma unroll
        for (int kk = 0; kk < 2; ++kk) {
            const int cl = kk * 4 + (lane >> 4);
            bf16x8 af[4], bfr[4];
#pragma unroll
            for (int m = 0; m < 4; ++m) {
                int row = wm + m * 16 + (lane & 15);
                af[m] = *(const bf16x8*)&buf[row * 64 + ((cl ^ (row & 7)) * 8)];
            }
#pragma unroll
            for (int n = 0; n < 4; ++n) {
                int row = wn + n * 16 + (lane & 15);
                bfr[n] = *(const bf16x8*)&buf[16384 + row * 64 + ((cl ^ (row & 7)) * 8)];
            }
#pragma unroll
            for (int m = 0; m < 4; ++m)
#pragma unroll
                for (int n = 0; n < 4; ++n)
                    acc[m][n] = __builtin_amdgcn_mfma_f32_16x16x32_bf16(af[m], bfr[n], acc[m][n], 0, 0, 0);
        }
        if ((u & 7) == 7 && u != 31) {         // fold f/i/g into accc
#pragma unroll
            for (int m = 0; m < 4; ++m)
#pragma unroll
                for (int n = 0; n < 4; ++n)
#pragma unroll
                    for (int r = 0; r < 4; ++r) {
                        float v = acc[m][n][r];
                        accc[m][n][r] += (v > 0.f ? v : 0.f);
                        acc[m][n][r] = 0.f;
                    }
        }
    }

    const float* cb = cell + (long)b * 65536;
    float* co = out_c + (long)b * 65536;
    unsigned short* ogo = og16 + (long)b * 65536;
    unsigned short* cbo = cb16 + (long)b * 65536;
    const int r0 = (lane >> 4) * 4;
    const int c0 = lane & 15;
#pragma unroll
    for (int m = 0; m < 4; ++m)
#pragma unroll
        for (int n = 0; n < 4; ++n)
#pragma unroll
            for (int r = 0; r < 4; ++r) {
                int row = wm + m * 16 + r0 + r;        // o (0..255)
                int col = qh + wn + n * 16 + c0;       // q
                long idx = (long)row * 256 + col;
                float cv = accc[m][n][r] + cb[idx];
                co[idx] = cv;
                cbo[idx] = f2bf(cv);
                float v = acc[m][n][r];                // o-gate
                ogo[idx] = f2bf(v > 0.f ? v : 0.f);
            }
}

// ---------------------------------------------------------------------------
// Merged Woc chain: per (q-tile, batch) block:
//   Phase A: Sc[q_loc][i] = bf16( sum_j Woc[q][j] * c[b][i][j] )  (LDS)
//   Phase B: out_h[b][o][tq+q_loc] = ogate + relu( sum_i Woc[o][i]*Sc[q_loc][i] )
//            (ogate read bf16 from og16; out_h written ONCE, no RMW)
// grid (2,128) = 256 blocks, 256 thr, 128KB LDS.
// ---------------------------------------------------------------------------
__global__ __launch_bounds__(256)
void gemm_woc(const unsigned short* __restrict__ Wocb,
              const unsigned short* __restrict__ cb16,
              const unsigned short* __restrict__ og16,
              float* __restrict__ out_h)
{
    __shared__ alignas(16) unsigned short stg[32768];   // 2 x (A 8192 | B 8192)
    __shared__ alignas(16) unsigned short Sc[32768];    // [128][256] swizzled bf16

    const int tid = threadIdx.x;
    const int lane = tid & 63;
    const int w = tid >> 6;

    int orig = blockIdx.x + 2 * blockIdx.y;              // 0..255
    int swz = (orig & 7) * 32 + (orig >> 3);             // bijective (256%8==0)
    const int b = swz >> 1;
    const int tq = (swz & 1) * 128;
    const int wm = (w >> 1) * 64;
    const int wn = (w & 1) * 64;
    const int r0 = (lane >> 4) * 4;
    const int c0 = lane & 15;

    // ---- Phase A: build Sc (q-tile x 256 i) ----
#pragma unroll
    for (int t2 = 0; t2 < 2; ++t2) {
        const unsigned short* Ap = Wocb + (long)tq * 256;
        const unsigned short* Bp = cb16 + (long)b * 65536 + (long)(t2 * 128) * 256;

        f32x4 acc[4][4];
#pragma unroll
        for (int m = 0; m < 4; ++m)
#pragma unroll
            for (int n = 0; n < 4; ++n)
                acc[m][n] = (f32x4){0.f, 0.f, 0.f, 0.f};

        stage_pair(Ap, 256, Bp, 256, stg, 0, tid);
#pragma unroll
        for (int t = 0; t < 4; ++t) {
            __syncthreads();
            if (t + 1 < 4)
                stage_pair(Ap, 256, Bp, 256, stg + ((t + 1) & 1) * 16384, (t + 1) * 64, tid);
            compute_tile(stg + (t & 1) * 16384, lane, wm, wn, acc);  // acc[q_loc][i_loc]
        }
        // write acc -> Sc bf16, swizzled (chunk-XOR within each 64-el group)
#pragma unroll
        for (int m = 0; m < 4; ++m)
#pragma unroll
            for (int n = 0; n < 4; ++n)
#pragma unroll
                for (int r = 0; r < 4; ++r) {
                    int qrow = wm + m * 16 + r0 + r;             // 0..127
                    int icol = t2 * 128 + wn + n * 16 + c0;      // 0..255
                    int addr = qrow * 256 + (icol & ~63)
                             + ((((icol >> 3) & 7) ^ (qrow & 7)) * 8) + (icol & 7);
                    Sc[addr] = f2bf(acc[m][n][r]);
                }
    }

    // ---- Phase B: out_h[o][tq+q] = ogate + relu( Woc[o,:] . Sc[q,:] ) ----
    float* ho = out_h + (long)b * 65536;
    const unsigned short* ogb = og16 + (long)b * 65536;
#pragma unroll
    for (int ot = 0; ot < 2; ++ot) {
        const unsigned short* Ap = Wocb + (long)(ot * 128) * 256;

        f32x4 acc[4][4];
#pragma unroll
        for (int m = 0; m < 4; ++m)
#pragma unroll
            for (int n = 0; n < 4; ++n)
                acc[m][n] = (f32x4){0.f, 0.f, 0.f, 0.f};

        stage_one(Ap, 256, stg, 0, tid);
#pragma unroll
        for (int t = 0; t < 4; ++t) {
            __syncthreads();   // first iter also fences Sc writes from phase A
            if (t + 1 < 4)
                stage_one(Ap, 256, stg + ((t + 1) & 1) * 16384, (t + 1) * 64, tid);
            compute_bsc(stg + (t & 1) * 16384, Sc, t * 64, lane, wm, wn, acc);
        }
#pragma unroll
        for (int m = 0; m < 4; ++m)
#pragma unroll
            for (int n = 0; n < 4; ++n)
#pragma unroll
                for (int r = 0; r < 4; ++r) {
                    int orow = ot * 128 + wm + m * 16 + r0 + r;
                    int qcol = tq + wn + n * 16 + c0;
                    long idx = (long)orow * 256 + qcol;
                    float v = acc[m][n][r];
                    ho[idx] = bf2f(ogb[idx]) + (v > 0.f ? v : 0.f);
                }
    }
}

// ---------------------------------------------------------------------------
extern "C" void kernel_launch(void* const* d_in, const int* in_sizes, int n_in,
                              void* d_out, int out_size, void* d_ws, size_t ws_size,
                              hipStream_t stream)
{
    (void)in_sizes; (void)n_in; (void)out_size; (void)ws_size;

    const float* X    = (const float*)d_in[0];
    const float* H    = (const float*)d_in[1];
    const float* cell = (const float*)d_in[2];
    const float* Wxp[4] = {(const float*)d_in[3], (const float*)d_in[4],
                           (const float*)d_in[5], (const float*)d_in[6]};
    const float* Whp[4] = {(const float*)d_in[7], (const float*)d_in[8],
                           (const float*)d_in[9], (const float*)d_in[10]};
    const float* Wocf = (const float*)d_in[11];

    float* out_h = (float*)d_out;                  // [128][256][256]
    float* out_c = out_h + 8388608;                // [128][256][256]

    unsigned short* ws   = (unsigned short*)d_ws;  // bf16 elements (ws = 256 MiB)
    unsigned short* XHb  = ws;                     // 16,777,216 el [2][128][256][256]
    unsigned short* Wcat = ws + 16777216;          //    524,288 el [4][256][512]
    unsigned short* Wocb = ws + 17301504;          //     65,536 el
    unsigned short* Tcat = ws + 17367040;          // 67,108,864 el [4][128][256][512]
    unsigned short* cb16 = ws + 84475904;          //  8,388,608 el (c bf16, natural)
    unsigned short* og16 = ws + 92864512;          //  8,388,608 el (relu(o) bf16)

    // 1. all conversions (X,H streaming + weights)
    cvt_all<<<dim3(10496), 256, 0, stream>>>(X, H, XHb,
                                             Wxp[0], Wxp[1], Wxp[2], Wxp[3],
                                             Whp[0], Whp[1], Whp[2], Whp[3],
                                             Wocf, Wcat, Wocb);
    // 2. stage 1, B-resident read-once: S_T[g][b][q][i']
    gemm_s1r<<<dim3(2, 128, 2), 512, 0, stream>>>(Wcat, XHb, Tcat);
    // 3. stage 2, Tcat read-once: 4 gates -> out_c (+bf16 copy) + og16 (bf16)
    gemm_gateBq<<<dim3(2, 128), 512, 0, stream>>>(Tcat, Wcat, cell, out_c, og16, cb16);
    // 4. merged Woc chain: Sc in LDS, h = ogate + relu(Woc . (Woc . c^T)^T)
    gemm_woc<<<dim3(2, 128), 256, 0, stream>>>(Wocb, cb16, og16, out_h);
}

// Round 19
// 167.520 us; speedup vs baseline: 1.0373x; 1.0077x over previous
//
#include <hip/hip_runtime.h>

typedef __bf16 bf16x8 __attribute__((ext_vector_type(8)));
typedef float f32x4 __attribute__((ext_vector_type(4)));

__device__ __forceinline__ unsigned short f2bf(float f) {
    unsigned int u = __builtin_bit_cast(unsigned int, f);
    u += 0x7fff + ((u >> 16) & 1);   // round-to-nearest-even (finite inputs)
    return (unsigned short)(u >> 16);
}
__device__ __forceinline__ float bf2f(unsigned short u) {
    unsigned int v = (unsigned int)u << 16;
    return __builtin_bit_cast(float, v);
}

// ---------------------------------------------------------------------------
// Stage a 128x64 A-tile + 128x64 B-tile (bf16) into lds[0..8191]/[8192..16383]
// via global_load_lds. Source chunk pre-swizzled c^(row&7); read side applies
// the same XOR (both-sides-or-neither, rule #21). 256 threads x 4 iters.
// ---------------------------------------------------------------------------
__device__ __forceinline__ void stage_pair(
    const unsigned short* __restrict__ Ap, int lda,
    const unsigned short* __restrict__ Bp, int ldb,
    unsigned short* lds, int k0, int tid)
{
#pragma unroll
    for (int it = 0; it < 4; ++it) {
        int li = it * 256 + tid;          // 0..1023: row = li>>3, chunk = li&7
        int row = li >> 3;
        int sc = ((li & 7) ^ (row & 7)) * 8;
        __builtin_amdgcn_global_load_lds(
            (const __attribute__((address_space(1))) void*)(Ap + (long)row * lda + k0 + sc),
            (__attribute__((address_space(3))) void*)&lds[li * 8], 16, 0, 0);
        __builtin_amdgcn_global_load_lds(
            (const __attribute__((address_space(1))) void*)(Bp + (long)row * ldb + k0 + sc),
            (__attribute__((address_space(3))) void*)&lds[8192 + li * 8], 16, 0, 0);
    }
}

// Stage just one 128x64 A-tile (8192 el) into buf (256 thr).
__device__ __forceinline__ void stage_one(
    const unsigned short* __restrict__ Ap, int lda,
    unsigned short* buf, int k0, int tid)
{
#pragma unroll
    for (int it = 0; it < 4; ++it) {
        int li = it * 256 + tid;
        int row = li >> 3;
        int sc = ((li & 7) ^ (row & 7)) * 8;
        __builtin_amdgcn_global_load_lds(
            (const __attribute__((address_space(1))) void*)(Ap + (long)row * lda + k0 + sc),
            (__attribute__((address_space(3))) void*)&buf[li * 8], 16, 0, 0);
    }
}

// ---------------------------------------------------------------------------
// One 64-deep K-step from a staged tile pair (swizzled read), 4-wave form.
// ---------------------------------------------------------------------------
__device__ __forceinline__ void compute_tile(
    const unsigned short* lds, int lane, int wm, int wn, f32x4 (&acc)[4][4])
{
#pragma unroll
    for (int kk = 0; kk < 2; ++kk) {
        const int cl = kk * 4 + (lane >> 4);
        bf16x8 af[4], bfr[4];
#pragma unroll
        for (int m = 0; m < 4; ++m) {
            int row = wm + m * 16 + (lane & 15);
            af[m] = *(const bf16x8*)&lds[row * 64 + ((cl ^ (row & 7)) * 8)];
        }
#pragma unroll
        for (int n = 0; n < 4; ++n) {
            int row = wn + n * 16 + (lane & 15);
            bfr[n] = *(const bf16x8*)&lds[8192 + row * 64 + ((cl ^ (row & 7)) * 8)];
        }
#pragma unroll
        for (int m = 0; m < 4; ++m)
#pragma unroll
            for (int n = 0; n < 4; ++n)
                acc[m][n] = __builtin_amdgcn_mfma_f32_16x16x32_bf16(af[m], bfr[n], acc[m][n], 0, 0, 0);
    }
}

// Like compute_tile but B-fragments come from a [rows][256] swizzled LDS
// buffer at K-offset k0 (A from a staged 128x64-style buffer, 64-wide rows).
__device__ __forceinline__ void compute_bsc(
    const unsigned short* bufA, const unsigned short* Sc, int k0,
    int lane, int wm, int wn, f32x4 (&acc)[4][4])
{
#pragma unroll
    for (int kk = 0; kk < 2; ++kk) {
        const int cl = kk * 4 + (lane >> 4);
        bf16x8 af[4], bfr[4];
#pragma unroll
        for (int m = 0; m < 4; ++m) {
            int row = wm + m * 16 + (lane & 15);
            af[m] = *(const bf16x8*)&bufA[row * 64 + ((cl ^ (row & 7)) * 8)];
        }
#pragma unroll
        for (int n = 0; n < 4; ++n) {
            int row = wn + n * 16 + (lane & 15);
            bfr[n] = *(const bf16x8*)&Sc[row * 256 + k0 + ((cl ^ (row & 7)) * 8)];
        }
#pragma unroll
        for (int m = 0; m < 4; ++m)
#pragma unroll
            for (int n = 0; n < 4; ++n)
                acc[m][n] = __builtin_amdgcn_mfma_f32_16x16x32_bf16(af[m], bfr[n], acc[m][n], 0, 0, 0);
    }
}

// ---------------------------------------------------------------------------
// Fused conversions: blocks [0,8192): X,H fp32->bf16 streaming;
// blocks [8192,10496): Wcat[g][q][512]=[Wgx|Wgh] bf16 + Woc bf16.
// ---------------------------------------------------------------------------
__global__ __launch_bounds__(256)
void cvt_all(const float* __restrict__ X, const float* __restrict__ H,
             unsigned short* __restrict__ XHb,
             const float* __restrict__ fx, const float* __restrict__ ix,
             const float* __restrict__ ox, const float* __restrict__ gx,
             const float* __restrict__ fh, const float* __restrict__ ih,
             const float* __restrict__ oh, const float* __restrict__ gh,
             const float* __restrict__ oc,
             unsigned short* __restrict__ Wcat, unsigned short* __restrict__ Wocb)
{
    int bid = blockIdx.x;
    if (bid < 8192) {
        long e = ((long)bid * 256 + threadIdx.x) * 8;
        const float* s = (e < 8388608) ? (X + e) : (H + (e - 8388608));
        float4 a = *(const float4*)s;
        float4 c = *(const float4*)(s + 4);
        uint4 uv;
        uv.x = (unsigned)f2bf(a.x) | ((unsigned)f2bf(a.y) << 16);
        uv.y = (unsigned)f2bf(a.z) | ((unsigned)f2bf(a.w) << 16);
        uv.z = (unsigned)f2bf(c.x) | ((unsigned)f2bf(c.y) << 16);
        uv.w = (unsigned)f2bf(c.z) | ((unsigned)f2bf(c.w) << 16);
        *(uint4*)&XHb[e] = uv;
    } else {
        int idx = (bid - 8192) * 256 + threadIdx.x;
        if (idx < 524288) {
            int g = idx >> 17;
            int rem = idx & 131071;
            int q = rem >> 9;
            int j = rem & 511;
            const float* xs = (g == 0) ? fx : (g == 1) ? ix : (g == 2) ? ox : gx;
            const float* hs = (g == 0) ? fh : (g == 1) ? ih : (g == 2) ? oh : gh;
            float v = (j < 256) ? xs[q * 256 + j] : hs[q * 256 + (j - 256)];
            Wcat[idx] = f2bf(v);
        } else if (idx < 589824) {
            int k = idx - 524288;
            Wocb[k] = f2bf(oc[k]);
        }
    }
}

// ---------------------------------------------------------------------------
// Stage 1, B-panel-resident (read-once): block = (b, hf, ti-half 128 i rows),
// all 256 q, loops all 4 gates over ONE resident XHb panel:
//   S_T[g][b][q][hf*256+ti+i] = sum_j Wcat[g][q][hf*256+j] * M_hf[b][ti+i][j]
// B (M panel, 128x256) resident in LDS (64KB, swizzled); A (Wcat, 256 q x 64)
// staged dbuf 2x32KB. 512 thr / 8 waves (q 4 x i 2 tiles of 64x64).
// grid (2,128,2) = 512 blocks, bijective XCD swizzle, 128KB LDS (1 blk/CU).
// ---------------------------------------------------------------------------
__global__ __launch_bounds__(512)
void gemm_s1r(const unsigned short* __restrict__ Wcat,
              const unsigned short* __restrict__ XHb,
              unsigned short* __restrict__ Tcat)
{
    __shared__ alignas(16) unsigned short lds[65536]; // B 32768 | A0 16384 | A1 16384

    const int tid = threadIdx.x;
    const int lane = tid & 63;
    const int w = tid >> 6;            // 0..7

    int d = blockIdx.x + 2 * blockIdx.y + 256 * blockIdx.z;  // 0..511
    int swz = (d & 7) * 64 + (d >> 3);                       // bijective (512%8==0)
    const int ti = (swz & 1) * 128;
    const int b = (swz >> 1) & 127;
    const int hf = swz >> 8;
    const int wm = (w >> 1) * 64;      // q offset (0..192)
    const int wn = (w & 1) * 64;       // i offset (0 or 64)

    const unsigned short* Bsrc = XHb + (long)hf * 8388608 + (long)b * 65536 + (long)ti * 256;
    unsigned short* Bres = lds;                       // [128][256] swizzled
    unsigned short* Abuf0 = lds + 32768;
    unsigned short* Abuf1 = lds + 49152;

    // stage resident B panel: 4096 chunks, pre-swizzled source, linear dest
#pragma unroll
    for (int it = 0; it < 8; ++it) {
        int li = it * 512 + tid;       // 0..4095: row = li>>5, ck = li&31
        int row = li >> 5;
        int ck = li & 31;
        int srccol = (ck & ~7) * 8 + (((ck & 7) ^ (row & 7)) * 8);
        __builtin_amdgcn_global_load_lds(
            (const __attribute__((address_space(1))) void*)(Bsrc + (long)row * 256 + srccol),
            (__attribute__((address_space(3))) void*)&Bres[li * 8], 16, 0, 0);
    }

    // stage A(u): gate = u>>2, t = u&3; A rows = 256 q x 64 j-chunk
    auto stageA = [&](int u, unsigned short* buf) {
        int gate = u >> 2;
        int t = u & 3;
        const unsigned short* Ap = Wcat + (long)gate * 131072 + hf * 256 + t * 64;
#pragma unroll
        for (int it = 0; it < 4; ++it) {
            int li = it * 512 + tid;   // 0..2047: row = li>>3 (0..255), ck = li&7
            int row = li >> 3;
            int sc = ((li & 7) ^ (row & 7)) * 8;
            __builtin_amdgcn_global_load_lds(
                (const __attribute__((address_space(1))) void*)(Ap + (long)row * 512 + sc),
                (__attribute__((address_space(3))) void*)&buf[li * 8], 16, 0, 0);
        }
    };

    f32x4 acc[4][4];
#pragma unroll
    for (int m = 0; m < 4; ++m)
#pragma unroll
        for (int n = 0; n < 4; ++n)
            acc[m][n] = (f32x4){0.f, 0.f, 0.f, 0.f};

    const int r0 = (lane >> 4) * 4;
    const int c0 = lane & 15;

    stageA(0, Abuf0);
    for (int u = 0; u < 16; ++u) {
        __syncthreads();   // loads(u) landed; all waves done compute(u-1)
        if (u + 1 < 16) stageA(u + 1, (u & 1) ? Abuf0 : Abuf1);
        const unsigned short* bufA = (u & 1) ? Abuf1 : Abuf0;
        compute_bsc(bufA, Bres, (u & 3) * 64, lane, wm, wn, acc);  // acc[q][i]
        if ((u & 3) == 3) {            // gate finished: write S_T[gate]
            int gate = u >> 2;
            unsigned short* Cb = Tcat + (long)gate * 16777216 + (long)b * 131072;
#pragma unroll
            for (int m = 0; m < 4; ++m)
#pragma unroll
                for (int n = 0; n < 4; ++n)
#pragma unroll
                    for (int r = 0; r < 4; ++r) {
                        int row = wm + m * 16 + r0 + r;                    // q
                        int col = hf * 256 + ti + wn + n * 16 + c0;        // i'
                        Cb[(long)row * 512 + col] = f2bf(acc[m][n][r]);
                        acc[m][n][r] = 0.f;
                    }
        }
    }
}

// ---------------------------------------------------------------------------
// Stage 2, Tcat-read-once: block = 256 o x 128 q (q-halves partition Tcat),
// all 4 gates (K=2048, 32 steps of 64, 2-phase dbuf).
//   out_c = cell + relu(f)+relu(i)+relu(g) (fp32 + bf16 copy);
//   og16  = bf16( relu(o-gate) )   [bf16 intermediate, consumed by gemm_woc]
// A = Wcat[gv] all 256 o (32KB/step, L2-resident); B = Tcat[gv][b][q-half]
// (16KB/step, read ONCE). 512 thr / 8 waves (o 4 x q 2 tiles), 96KB LDS.
// grid (2,128) = 256 blocks, bijective XCD swizzle.
// ---------------------------------------------------------------------------
__global__ __launch_bounds__(512)
void gemm_gateBq(const unsigned short* __restrict__ Tcat,
                 const unsigned short* __restrict__ Wcat,
                 const float* __restrict__ cell,
                 float* __restrict__ out_c,
                 unsigned short* __restrict__ og16,
                 unsigned short* __restrict__ cb16)
{
    __shared__ alignas(16) unsigned short lds[49152];   // 2 x (A 16384 | B 8192)

    const int tid = threadIdx.x;
    const int lane = tid & 63;
    const int w = tid >> 6;            // 0..7

    int orig = blockIdx.x + 2 * blockIdx.y;              // 0..255
    int swz = (orig & 7) * 32 + (orig >> 3);             // bijective (256%8==0)
    const int b = swz >> 1;
    const int qh = (swz & 1) * 128;
    const int wm = (w >> 1) * 64;      // o offset (0..192)
    const int wn = (w & 1) * 64;       // q offset (0 or 64)

    const unsigned short* Bb = Tcat + (long)b * 131072 + (long)qh * 512;

    // stage step u into buf: A = Wcat[gv] 256x64, B = Tcat panel 128x64
    auto stage = [&](int u, unsigned short* buf) {
        int s = u >> 3;
        int gv = s ^ (s >> 1);                 // {0,1,3,2} = f,i,g,o
        int k0 = (u & 7) * 64;
        const unsigned short* Ap = Wcat + (long)gv * 131072 + k0;
        const unsigned short* Bp = Bb + (long)gv * 16777216 + k0;
#pragma unroll
        for (int it = 0; it < 4; ++it) {
            int li = it * 512 + tid;           // A: 0..2047, row 0..255
            int row = li >> 3;
            int sc = ((li & 7) ^ (row & 7)) * 8;
            __builtin_amdgcn_global_load_lds(
                (const __attribute__((address_space(1))) void*)(Ap + (long)row * 512 + sc),
                (__attribute__((address_space(3))) void*)&buf[li * 8], 16, 0, 0);
        }
#pragma unroll
        for (int it = 0; it < 2; ++it) {
            int li = it * 512 + tid;           // B: 0..1023, row 0..127
            int row = li >> 3;
            int sc = ((li & 7) ^ (row & 7)) * 8;
            __builtin_amdgcn_global_load_lds(
                (const __attribute__((address_space(1))) void*)(Bp + (long)row * 512 + sc),
                (__attribute__((address_space(3))) void*)&buf[16384 + li * 8], 16, 0, 0);
        }
    };

    f32x4 accc[4][4], acc[4][4];
#pragma unroll
    for (int m = 0; m < 4; ++m)
#pragma unroll
        for (int n = 0; n < 4; ++n) {
            accc[m][n] = (f32x4){0.f, 0.f, 0.f, 0.f};
            acc[m][n] = (f32x4){0.f, 0.f, 0.f, 0.f};
        }

    stage(0, lds);
    for (int u = 0; u < 32; ++u) {
        __syncthreads();   // loads(u) landed; all waves done compute(u-1)
        if (u + 1 < 32) stage(u + 1, lds + ((u + 1) & 1) * 24576);
        const unsigned short* buf = lds + (u & 1) * 24576;
        // compute: A rows o (wm), B rows q (wn)
#pragma unroll
        for (int kk = 0; kk < 2; ++kk) {
            const int cl = kk * 4 + (lane >> 4);
            bf16x8 af[4], bfr[4];
#pragma unroll
            for (int m = 0; m < 4; ++m) {
                int row = wm + m * 16 + (lane & 15);
                af[m] = *(const bf16x8*)&buf[row * 64 + ((cl ^ (row & 7)) * 8)];
            }
#pragma unroll
            for (int n = 0; n < 4; ++n) {
                int row = wn + n * 16 + (lane & 15);
                bfr[n] = *(const bf16x8*)&buf[16384 + row * 64 + ((cl ^ (row & 7)) * 8)];
            }
#pragma unroll
            for (int m = 0; m < 4; ++m)
#pragma unroll
                for (int n = 0; n < 4; ++n)
                    acc[m][n] = __builtin_amdgcn_mfma_f32_16x16x32_bf16(af[m], bfr[n], acc[m][n], 0, 0, 0);
        }
        if ((u & 7) == 7 && u != 31) {         // fold f/i/g into accc
#pragma unroll
            for (int m = 0; m < 4; ++m)
#pragma unroll
                for (int n = 0; n < 4; ++n)
#pragma unroll
                    for (int r = 0; r < 4; ++r) {
                        float v = acc[m][n][r];
                        accc[m][n][r] += (v > 0.f ? v : 0.f);
                        acc[m][n][r] = 0.f;
                    }
        }
    }

    const float* cb = cell + (long)b * 65536;
    float* co = out_c + (long)b * 65536;
    unsigned short* ogo = og16 + (long)b * 65536;
    unsigned short* cbo = cb16 + (long)b * 65536;
    const int r0 = (lane >> 4) * 4;
    const int c0 = lane & 15;
#pragma unroll
    for (int m = 0; m < 4; ++m)
#pragma unroll
        for (int n = 0; n < 4; ++n)
#pragma unroll
            for (int r = 0; r < 4; ++r) {
                int row = wm + m * 16 + r0 + r;        // o (0..255)
                int col = qh + wn + n * 16 + c0;       // q
                long idx = (long)row * 256 + col;
                float cv = accc[m][n][r] + cb[idx];
                co[idx] = cv;
                cbo[idx] = f2bf(cv);
                float v = acc[m][n][r];                // o-gate
                ogo[idx] = f2bf(v > 0.f ? v : 0.f);
            }
}

// ---------------------------------------------------------------------------
// Merged Woc chain: per (q-tile, batch) block:
//   Phase A: Sc[q_loc][i] = bf16( sum_j Woc[q][j] * c[b][i][j] )  (LDS)
//   Phase B: out_h[b][o][tq+q_loc] = ogate + relu( sum_i Woc[o][i]*Sc[q_loc][i] )
//            (ogate read bf16 from og16; out_h written ONCE, no RMW)
// grid (2,128) = 256 blocks, 256 thr, 128KB LDS.
// ---------------------------------------------------------------------------
__global__ __launch_bounds__(256)
void gemm_woc(const unsigned short* __restrict__ Wocb,
              const unsigned short* __restrict__ cb16,
              const unsigned short* __restrict__ og16,
              float* __restrict__ out_h)
{
    __shared__ alignas(16) unsigned short stg[32768];   // 2 x (A 8192 | B 8192)
    __shared__ alignas(16) unsigned short Sc[32768];    // [128][256] swizzled bf16

    const int tid = threadIdx.x;
    const int lane = tid & 63;
    const int w = tid >> 6;

    int orig = blockIdx.x + 2 * blockIdx.y;              // 0..255
    int swz = (orig & 7) * 32 + (orig >> 3);             // bijective (256%8==0)
    const int b = swz >> 1;
    const int tq = (swz & 1) * 128;
    const int wm = (w >> 1) * 64;
    const int wn = (w & 1) * 64;
    const int r0 = (lane >> 4) * 4;
    const int c0 = lane & 15;

    // ---- Phase A: build Sc (q-tile x 256 i) ----
#pragma unroll
    for (int t2 = 0; t2 < 2; ++t2) {
        const unsigned short* Ap = Wocb + (long)tq * 256;
        const unsigned short* Bp = cb16 + (long)b * 65536 + (long)(t2 * 128) * 256;

        f32x4 acc[4][4];
#pragma unroll
        for (int m = 0; m < 4; ++m)
#pragma unroll
            for (int n = 0; n < 4; ++n)
                acc[m][n] = (f32x4){0.f, 0.f, 0.f, 0.f};

        stage_pair(Ap, 256, Bp, 256, stg, 0, tid);
#pragma unroll
        for (int t = 0; t < 4; ++t) {
            __syncthreads();
            if (t + 1 < 4)
                stage_pair(Ap, 256, Bp, 256, stg + ((t + 1) & 1) * 16384, (t + 1) * 64, tid);
            compute_tile(stg + (t & 1) * 16384, lane, wm, wn, acc);  // acc[q_loc][i_loc]
        }
        // write acc -> Sc bf16, swizzled (chunk-XOR within each 64-el group)
#pragma unroll
        for (int m = 0; m < 4; ++m)
#pragma unroll
            for (int n = 0; n < 4; ++n)
#pragma unroll
                for (int r = 0; r < 4; ++r) {
                    int qrow = wm + m * 16 + r0 + r;             // 0..127
                    int icol = t2 * 128 + wn + n * 16 + c0;      // 0..255
                    int addr = qrow * 256 + (icol & ~63)
                             + ((((icol >> 3) & 7) ^ (qrow & 7)) * 8) + (icol & 7);
                    Sc[addr] = f2bf(acc[m][n][r]);
                }
    }

    // ---- Phase B: out_h[o][tq+q] = ogate + relu( Woc[o,:] . Sc[q,:] ) ----
    float* ho = out_h + (long)b * 65536;
    const unsigned short* ogb = og16 + (long)b * 65536;
#pragma unroll
    for (int ot = 0; ot < 2; ++ot) {
        const unsigned short* Ap = Wocb + (long)(ot * 128) * 256;

        f32x4 acc[4][4];
#pragma unroll
        for (int m = 0; m < 4; ++m)
#pragma unroll
            for (int n = 0; n < 4; ++n)
                acc[m][n] = (f32x4){0.f, 0.f, 0.f, 0.f};

        stage_one(Ap, 256, stg, 0, tid);
#pragma unroll
        for (int t = 0; t < 4; ++t) {
            __syncthreads();   // first iter also fences Sc writes from phase A
            if (t + 1 < 4)
                stage_one(Ap, 256, stg + ((t + 1) & 1) * 16384, (t + 1) * 64, tid);
            compute_bsc(stg + (t & 1) * 16384, Sc, t * 64, lane, wm, wn, acc);
        }
#pragma unroll
        for (int m = 0; m < 4; ++m)
#pragma unroll
            for (int n = 0; n < 4; ++n)
#pragma unroll
                for (int r = 0; r < 4; ++r) {
                    int orow = ot * 128 + wm + m * 16 + r0 + r;
                    int qcol = tq + wn + n * 16 + c0;
                    long idx = (long)orow * 256 + qcol;
                    float v = acc[m][n][r];
                    ho[idx] = bf2f(ogb[idx]) + (v > 0.f ? v : 0.f);
                }
    }
}

// ---------------------------------------------------------------------------
extern "C" void kernel_launch(void* const* d_in, const int* in_sizes, int n_in,
                              void* d_out, int out_size, void* d_ws, size_t ws_size,
                              hipStream_t stream)
{
    (void)in_sizes; (void)n_in; (void)out_size; (void)ws_size;

    const float* X    = (const float*)d_in[0];
    const float* H    = (const float*)d_in[1];
    const float* cell = (const float*)d_in[2];
    const float* Wxp[4] = {(const float*)d_in[3], (const float*)d_in[4],
                           (const float*)d_in[5], (const float*)d_in[6]};
    const float* Whp[4] = {(const float*)d_in[7], (const float*)d_in[8],
                           (const float*)d_in[9], (const float*)d_in[10]};
    const float* Wocf = (const float*)d_in[11];

    float* out_h = (float*)d_out;                  // [128][256][256]
    float* out_c = out_h + 8388608;                // [128][256][256]

    unsigned short* ws   = (unsigned short*)d_ws;  // bf16 elements (ws = 256 MiB)
    unsigned short* XHb  = ws;                     // 16,777,216 el [2][128][256][256]
    unsigned short* Wcat = ws + 16777216;          //    524,288 el [4][256][512]
    unsigned short* Wocb = ws + 17301504;          //     65,536 el
    unsigned short* Tcat = ws + 17367040;          // 67,108,864 el [4][128][256][512]
    unsigned short* cb16 = ws + 84475904;          //  8,388,608 el (c bf16, natural)
    unsigned short* og16 = ws + 92864512;          //  8,388,608 el (relu(o) bf16)

    // 1. all conversions (X,H streaming + weights)
    cvt_all<<<dim3(10496), 256, 0, stream>>>(X, H, XHb,
                                             Wxp[0], Wxp[1], Wxp[2], Wxp[3],
                                             Whp[0], Whp[1], Whp[2], Whp[3],
                                             Wocf, Wcat, Wocb);
    // 2. stage 1, B-resident read-once: S_T[g][b][q][i']
    gemm_s1r<<<dim3(2, 128, 2), 512, 0, stream>>>(Wcat, XHb, Tcat);
    // 3. stage 2, Tcat read-once: 4 gates -> out_c (+bf16 copy) + og16 (bf16)
    gemm_gateBq<<<dim3(2, 128), 512, 0, stream>>>(Tcat, Wcat, cell, out_c, og16, cb16);
    // 4. merged Woc chain: Sc in LDS, h = ogate + relu(Woc . (Woc . c^T)^T)
    gemm_woc<<<dim3(2, 128), 256, 0, stream>>>(Wocb, cb16, og16, out_h);
}